// Round 1
// baseline (18136.465 us; speedup 1.0000x reference)
//
#include <hip/hip_runtime.h>
#include <hip/hip_fp16.h>

#define T_ 512
#define B_ 64
#define NINP_ 512
#define NHID_ 1024
#define NWG_ 128
#define HPW_ 8      // hidden units per WG
#define NCOL_ 32    // 4 gates * HPW_
#define KH_ 1024
#define LDSK_ 1544  // padded K stride (1536 + 8) in fp16 elems
#define GSTRIDE_ 33 // padded gate-exchange stride

typedef _Float16 half8v __attribute__((ext_vector_type(8)));
typedef _Float16 half4v __attribute__((ext_vector_type(4)));
typedef float f32x4 __attribute__((ext_vector_type(4)));

__global__ void cvt_f32_to_f16(const float4* __restrict__ in, half4v* __restrict__ out, int n4) {
  int idx = blockIdx.x * blockDim.x + threadIdx.x;
  if (idx < n4) {
    float4 v = in[idx];
    half4v h;
    h[0] = (_Float16)v.x; h[1] = (_Float16)v.y; h[2] = (_Float16)v.z; h[3] = (_Float16)v.w;
    out[idx] = h;
  }
}

__global__ void __launch_bounds__(256, 1) lstm_persist(
    const float* __restrict__ mask,
    const float* __restrict__ Wih_e, const float* __restrict__ Whh_e,
    const float* __restrict__ bih_e, const float* __restrict__ bhh_e,
    const float* __restrict__ Wih_d, const float* __restrict__ Whh_d,
    const float* __restrict__ bih_d, const float* __restrict__ bhh_d,
    const _Float16* __restrict__ xh,
    _Float16* __restrict__ hbuf0, _Float16* __restrict__ hbuf1,
    unsigned* __restrict__ bar,
    float* __restrict__ out)
{
  extern __shared__ char smem[];
  _Float16* wlds = (_Float16*)smem;                                   // NCOL_ * LDSK_
  float* glds = (float*)(smem + NCOL_ * LDSK_ * 2);                   // 64 * GSTRIDE_
  float* blds = (float*)(smem + NCOL_ * LDSK_ * 2 + 64 * GSTRIDE_ * 4); // NCOL_

  const int tid = threadIdx.x;
  const int wg = blockIdx.x;
  const int lane = tid & 63;
  const int wv = tid >> 6;
  const int hbase = wg * HPW_;

  auto load_w = [&](const float* Whh, const float* Wih, const float* bih, const float* bhh) {
    for (int n = 0; n < NCOL_; ++n) {
      const int gcol = (n >> 3) * NHID_ + hbase + (n & 7);
      const float* wh = Whh + (size_t)gcol * NHID_;
      const float* wi = Wih + (size_t)gcol * NINP_;
      for (int k = tid; k < KH_; k += 256) wlds[n * LDSK_ + k] = (_Float16)wh[k];
      for (int k = tid; k < NINP_; k += 256) wlds[n * LDSK_ + KH_ + k] = (_Float16)wi[k];
    }
    if (tid < NCOL_) {
      const int gcol = (tid >> 3) * NHID_ + hbase + (tid & 7);
      blds[tid] = bih[gcol] + bhh[gcol];
    }
  };

  load_w(Whh_e, Wih_e, bih_e, bhh_e);
  __syncthreads();

  float cst[2] = {0.f, 0.f};   // fp32 cell state, per-thread slice
  float hst[2] = {0.f, 0.f};   // fp32 hidden state, per-thread slice

  // MFMA fragment roles (gfx950 16x16x32, guide-verified layouts):
  //   A: lane holds A[m = lane&15][k = (lane>>4)*8 + j], j=0..7
  //   B: lane holds B[n = lane&15][k = (lane>>4)*8 + j]
  //   D: lane holds D[m = (lane>>4)*4 + r][n = lane&15]
  const int mrow = 16 * wv + (lane & 15);
  const int ksub = (lane >> 4) * 8;
  const int bcol0 = lane & 15;
  const _Float16* bp0 = wlds + (size_t)bcol0 * LDSK_ + ksub;
  const _Float16* bp1 = wlds + (size_t)(bcol0 + 16) * LDSK_ + ksub;

  const int em = tid >> 2;  // elementwise batch row
  const int ej = tid & 3;

  for (int t = 0; t < 2 * T_; ++t) {
    const bool dec = (t >= T_);
    const int ti = dec ? (t - T_) : t;
    if (t == T_) {
      load_w(Whh_d, Wih_d, bih_d, bhh_d);
      __syncthreads();
    }
    const _Float16* hprev = (t & 1) ? hbuf0 : hbuf1;
    _Float16* hnext = (t & 1) ? hbuf1 : hbuf0;

    f32x4 acc0 = {0.f, 0.f, 0.f, 0.f};
    f32x4 acc1 = {0.f, 0.f, 0.f, 0.f};

    const _Float16* ap = hprev + (size_t)mrow * NHID_ + ksub;
    #pragma unroll 8
    for (int kk = 0; kk < KH_; kk += 32) {
      half8v a = *(const half8v*)(ap + kk);
      half8v b0 = *(const half8v*)(bp0 + kk);
      half8v b1 = *(const half8v*)(bp1 + kk);
      acc0 = __builtin_amdgcn_mfma_f32_16x16x32_f16(a, b0, acc0, 0, 0, 0);
      acc1 = __builtin_amdgcn_mfma_f32_16x16x32_f16(a, b1, acc1, 0, 0, 0);
    }
    const _Float16* xp = xh + ((size_t)ti * B_ + mrow) * NINP_ + ksub;
    #pragma unroll 8
    for (int kk = 0; kk < NINP_; kk += 32) {
      half8v a = *(const half8v*)(xp + kk);
      half8v b0 = *(const half8v*)(bp0 + KH_ + kk);
      half8v b1 = *(const half8v*)(bp1 + KH_ + kk);
      acc0 = __builtin_amdgcn_mfma_f32_16x16x32_f16(a, b0, acc0, 0, 0, 0);
      acc1 = __builtin_amdgcn_mfma_f32_16x16x32_f16(a, b1, acc1, 0, 0, 0);
    }

    // gate exchange via LDS (D-layout -> per-(m,j) threads)
    #pragma unroll
    for (int r = 0; r < 4; ++r) {
      const int m = 16 * wv + (lane >> 4) * 4 + r;
      glds[m * GSTRIDE_ + bcol0] = acc0[r];
      glds[m * GSTRIDE_ + 16 + bcol0] = acc1[r];
    }
    __syncthreads();

    #pragma unroll
    for (int p = 0; p < 2; ++p) {
      const int j = ej + 4 * p;
      const float gi = glds[em * GSTRIDE_ + j]      + blds[j];
      const float gf = glds[em * GSTRIDE_ + 8 + j]  + blds[8 + j];
      const float gg = glds[em * GSTRIDE_ + 16 + j] + blds[16 + j];
      const float go = glds[em * GSTRIDE_ + 24 + j] + blds[24 + j];
      const float iv = 1.f / (1.f + expf(-gi));
      const float fv = 1.f / (1.f + expf(-gf));
      const float gv = tanhf(gg);
      const float ov = 1.f / (1.f + expf(-go));
      float cn = fv * cst[p] + iv * gv;
      float hn = ov * tanhf(cn);
      if (!dec) {
        const float mv = mask[ti * B_ + em];
        hn = hn * mv + hst[p] * (1.f - mv);
        cn = cn * mv + cst[p] * (1.f - mv);
      }
      cst[p] = cn; hst[p] = hn;
      hnext[(size_t)em * NHID_ + hbase + j] = (_Float16)hn;
      if (dec) out[((size_t)ti * B_ + em) * NHID_ + hbase + j] = hn;
    }

    // grid barrier (sense via monotonically increasing generation)
    __syncthreads();
    if (tid == 0) {
      __threadfence();  // release our h-writes device-wide
      unsigned old = __hip_atomic_fetch_add(&bar[0], 1u, __ATOMIC_ACQ_REL, __HIP_MEMORY_SCOPE_AGENT);
      if (old == NWG_ - 1) {
        __hip_atomic_store(&bar[0], 0u, __ATOMIC_RELAXED, __HIP_MEMORY_SCOPE_AGENT);
        __hip_atomic_store(&bar[32], (unsigned)(t + 1), __ATOMIC_RELEASE, __HIP_MEMORY_SCOPE_AGENT);
      } else {
        while (__hip_atomic_load(&bar[32], __ATOMIC_RELAXED, __HIP_MEMORY_SCOPE_AGENT) < (unsigned)(t + 1)) { }
        __threadfence();  // acquire others' h-writes (L1/L2 inv)
      }
    }
    __syncthreads();
  }
}

extern "C" void kernel_launch(void* const* d_in, const int* in_sizes, int n_in,
                              void* d_out, int out_size, void* d_ws, size_t ws_size,
                              hipStream_t stream) {
  const float* input = (const float*)d_in[0];
  const float* mask  = (const float*)d_in[1];
  const float* Wih_e = (const float*)d_in[2];
  const float* Whh_e = (const float*)d_in[3];
  const float* bih_e = (const float*)d_in[4];
  const float* bhh_e = (const float*)d_in[5];
  const float* Wih_d = (const float*)d_in[6];
  const float* Whh_d = (const float*)d_in[7];
  const float* bih_d = (const float*)d_in[8];
  const float* bhh_d = (const float*)d_in[9];
  float* out = (float*)d_out;
  char* ws = (char*)d_ws;

  unsigned* bar = (unsigned*)ws;
  _Float16* hbuf0 = (_Float16*)(ws + 4096);
  _Float16* hbuf1 = hbuf0 + B_ * NHID_;
  _Float16* xh = (_Float16*)(ws + 4096 + 2 * B_ * NHID_ * 2);

  // zero barrier + both h double-buffers (ws is poisoned 0xAA before each call)
  hipMemsetAsync(ws, 0, 4096 + 2 * B_ * NHID_ * 2, stream);

  const int n4 = T_ * B_ * NINP_ / 4;
  cvt_f32_to_f16<<<n4 / 256, 256, 0, stream>>>((const float4*)input, (half4v*)xh, n4);

  const size_t lds_bytes = (size_t)NCOL_ * LDSK_ * 2 + 64 * GSTRIDE_ * 4 + NCOL_ * 4;
  hipFuncSetAttribute((const void*)lstm_persist, hipFuncAttributeMaxDynamicSharedMemorySize, (int)lds_bytes);

  void* args[] = { (void*)&mask, (void*)&Wih_e, (void*)&Whh_e, (void*)&bih_e, (void*)&bhh_e,
                   (void*)&Wih_d, (void*)&Whh_d, (void*)&bih_d, (void*)&bhh_d,
                   (void*)&xh, (void*)&hbuf0, (void*)&hbuf1, (void*)&bar, (void*)&out };
  hipLaunchCooperativeKernel((void*)lstm_persist, dim3(NWG_), dim3(256), args,
                             (unsigned)lds_bytes, stream);
}